// Round 11
// baseline (63.520 us; speedup 1.0000x reference)
//
#include <hip/hip_runtime.h>

typedef _Float16 f16x8  __attribute__((ext_vector_type(8)));
typedef _Float16 f16x4  __attribute__((ext_vector_type(4)));
typedef __fp16   hf2    __attribute__((ext_vector_type(2)));
typedef float    f32x4  __attribute__((ext_vector_type(4)));
typedef float    f32x16 __attribute__((ext_vector_type(16)));

namespace {
constexpr int kN = 4, kL = 1024, kS = 1024, kH = 16, kE = 64, kD = 64;
constexpr int kRowF = kH * kE;     // 1024 floats: s-row stride of K and V
constexpr int KVB = 64;            // keys per LDS chunk
constexpr int NCH = kS / KVB;      // 16 chunks
constexpr float SCL = 0.125f * 1.44269504088896340736f;  // 1/sqrt(E)*log2(e)
}

__device__ __forceinline__ unsigned pku(float a, float b) {
  union { hf2 h; unsigned u; } u;
  u.h = __builtin_amdgcn_cvt_pkrtz(a, b);
  return u.u;
}
__device__ __forceinline__ f16x4 pk4(float a, float b, float c, float d) {
  union { hf2 h2[2]; f16x4 v; } u;
  u.h2[0] = __builtin_amdgcn_cvt_pkrtz(a, b);
  u.h2[1] = __builtin_amdgcn_cvt_pkrtz(c, d);
  return u.v;
}
// cross-half-wave max via permlane32_swap (VALU; replaces LDS shfl round-trip)
__device__ __forceinline__ float xmax32(float t) {
  union { float f; unsigned u; } tu; tu.f = t;
  auto P = __builtin_amdgcn_permlane32_swap(tu.u, tu.u, false, false);
  union { unsigned u; float f; } a, b; a.u = P[0]; b.u = P[1];
  return fmaxf(a.f, b.f);
}
__device__ __forceinline__ float xsum32(float t) {
  union { float f; unsigned u; } tu; tu.f = t;
  auto P = __builtin_amdgcn_permlane32_swap(tu.u, tu.u, false, false);
  union { unsigned u; float f; } a, b; a.u = P[0]; b.u = P[1];
  return a.f + b.f;
}

// RAW barrier: lgkmcnt(0)-only drain (LDS visibility is all the barrier must
// order; register-destined global loads legally stay in flight across it --
// this is the whole point vs __syncthreads' conservative vmcnt(0) fence).
#define BAR() do {                                            \
    asm volatile("s_waitcnt lgkmcnt(0)" ::: "memory");        \
    __builtin_amdgcn_s_barrier();                             \
    __builtin_amdgcn_sched_barrier(0);                        \
  } while (0)

// Round-6/10 verified math (fragments, swizzles, swapped scores, T12
// permlane P-redistribution, defer-max, lagged PV + 3-slot V rotation).
// This round: raw barriers (keep K/V prefetch in flight across them),
// permlane max, tree sum, masks loaded right after the barrier.
__global__ __launch_bounds__(256, 2)
void attn_fwd_kernel(const float* __restrict__ Q, const float* __restrict__ K,
                     const float* __restrict__ V, const float* __restrict__ M,
                     const float* __restrict__ KLN, float* __restrict__ O)
{
  __shared__ _Float16 Ks[2][KVB * 64];
  __shared__ _Float16 Vt[3][kD * 64];

  const int tid  = threadIdx.x;
  const int lane = tid & 63;
  const int wave = tid >> 6;      // 0..3
  const int l31  = lane & 31;     // q within wave-tile; also s/d row in frags
  const int hi   = lane >> 5;
  const int sr   = tid >> 4;      // staging row id 0..15
  const int sc4  = tid & 15;      // staging float4 column

  // XCD swizzle (512 % 8 == 0 -> bijective)
  const int swz = ((blockIdx.x & 7) << 6) | (blockIdx.x >> 3);
  const int nh = swz >> 3, qb = swz & 7;
  const int h = nh & (kH - 1), n = nh >> 4;
  const int qrow = qb * 128 + wave * 32 + l31;

  const float* Kp = K + ((size_t)n * kS * kH + h) * kE;
  const float* Vp = V + ((size_t)n * kS * kH + h) * kD;
  const float* Lp = KLN + (size_t)n * kS;
  const float* Mp = M + (size_t)qrow * kS;

  // ---- hoisted Q B-frags (pre-scaled): qf[ec], k = 16*ec + 8*hi + j ----
  f16x8 qf[4];
  {
    const float* Qp = Q + ((size_t)((size_t)n * kL + qrow) * kH + h) * kE;
    #pragma unroll
    for (int ec = 0; ec < 4; ++ec) {
      const f32x4 a = *reinterpret_cast<const f32x4*>(Qp + 16*ec + 8*hi);
      const f32x4 b = *reinterpret_cast<const f32x4*>(Qp + 16*ec + 8*hi + 4);
      union { f16x4 h4[2]; f16x8 v; } u;
      u.h4[0] = pk4(a[0]*SCL, a[1]*SCL, a[2]*SCL, a[3]*SCL);
      u.h4[1] = pk4(b[0]*SCL, b[1]*SCL, b[2]*SCL, b[3]*SCL);
      qf[ec] = u.v;
    }
  }

  // ---- per-thread LDS constants (verified round-6 math) ----
  const int kxor = (l31 & 7) << 1;
  int keyv[2], vrowb[2];
  #pragma unroll
  for (int dt = 0; dt < 2; ++dt) {
    const int d = 32*dt + l31;
    keyv[dt] = ((4*((d>>2)&3) + (d&3)) ^ (d>>2)) & 15;
    vrowb[dt] = d * 64;
  }
  int hwv[4];
  #pragma unroll
  for (int jd = 0; jd < 4; ++jd)
    hwv[jd] = ((4*(sc4 & 3) + jd) ^ sc4) & 15;

  const f32x16 z16 = {0,0,0,0, 0,0,0,0, 0,0,0,0, 0,0,0,0};
  f32x16 acc[2] = {z16, z16};
  float mrun = -1e30f, lsum = 0.f;

  // ---- staging helpers ----
  f32x4 ka[4], va[4];
  auto load_kv = [&](int sbase) {
    #pragma unroll
    for (int i = 0; i < 4; ++i)
      ka[i] = *reinterpret_cast<const f32x4*>(Kp + (size_t)(sbase + 16*i + sr) * kRowF + 4*sc4);
    #pragma unroll
    for (int js = 0; js < 4; ++js)
      va[js] = *reinterpret_cast<const f32x4*>(Vp + (size_t)(sbase + 4*sr + js) * kRowF + 4*sc4);
  };
  auto kv_write = [&](int kbuf, int vslot) {
    #pragma unroll
    for (int i = 0; i < 4; ++i) {
      const int s = 16*i + sr;
      *reinterpret_cast<f16x4*>(&Ks[kbuf][s*64 + ((sc4 ^ ((s & 7) << 1)) << 2)]) =
          pk4(ka[i][0], ka[i][1], ka[i][2], ka[i][3]);
    }
    #pragma unroll
    for (int jd = 0; jd < 4; ++jd) {
      const int d = 4*sc4 + jd;
      *reinterpret_cast<f16x4*>(&Vt[vslot][d*64 + ((sr ^ hwv[jd]) << 2)]) =
          pk4(va[0][jd], va[1][jd], va[2][jd], va[3][jd]);
    }
  };
  f16x8 pf[4] = {};   // P fragments of the previous chunk
  auto pv_step = [&](int vslot) {
    #pragma unroll
    for (int dt = 0; dt < 2; ++dt) {
      #pragma unroll
      for (int sc = 0; sc < 4; ++sc) {
        const int sl0 = ((sc << 2) + (hi << 1)) ^ keyv[dt];
        union { f16x4 h4[2]; f16x8 v; } vu;
        vu.h4[0] = *reinterpret_cast<const f16x4*>(&Vt[vslot][vrowb[dt] + (sl0 << 2)]);
        vu.h4[1] = *reinterpret_cast<const f16x4*>(&Vt[vslot][vrowb[dt] + ((sl0 ^ 1) << 2)]);
        acc[dt] = __builtin_amdgcn_mfma_f32_32x32x16_f16(vu.v, pf[sc], acc[dt], 0, 0, 0);
      }
    }
  };

  // ---- prologue: chunk 0 staged, chunk 1 in flight ----
  load_kv(0);
  kv_write(0, 0);
  load_kv(KVB);

  int sp = 2, scur = 0, sn = 1;   // V slots: (c-1)%3, c%3, (c+1)%3

  for (int c = 0; c < NCH; ++c) {
    const int kcur = c & 1;
    const int s0 = c * KVB;
    BAR();

    // mask / key_lengths loads first: covered by QK+PV below
    f32x4 mv[2][4], lv[2][4];
    #pragma unroll
    for (int st = 0; st < 2; ++st)
      #pragma unroll
      for (int m = 0; m < 4; ++m) {
        mv[st][m] = *reinterpret_cast<const f32x4*>(Mp + s0 + 32*st + 8*m + 4*hi);
        lv[st][m] = *reinterpret_cast<const f32x4*>(Lp + s0 + 32*st + 8*m + 4*hi);
      }

    if (c + 1 < NCH) kv_write(kcur ^ 1, sn);   // chunk c+1 (loaded body c-1)
    if (c + 2 < NCH) load_kv((c + 2) * KVB);   // stays in flight across BAR

    // ---- QK^T(c): 2 s-tiles x 4 e-chunks of 32x32x16 ----
    f32x16 xc[2];
    __builtin_amdgcn_s_setprio(1);
    #pragma unroll
    for (int st = 0; st < 2; ++st) {
      f32x16 cc = z16;
      #pragma unroll
      for (int ec = 0; ec < 4; ++ec) {
        const f16x8 kf = *reinterpret_cast<const f16x8*>(
            &Ks[kcur][l31*64 + st*2048 + ((((ec << 2) + (hi << 1)) ^ kxor) << 2)]);
        cc = __builtin_amdgcn_mfma_f32_32x32x16_f16(kf, qf[ec], cc, 0, 0, 0);
      }
      xc[st] = cc;
    }

    // ---- PV(c-1): trails one chunk ----
    if (c > 0) pv_step(sp);
    __builtin_amdgcn_s_setprio(0);

    // ---- logits(c) ----
    float x[2][16];
    #pragma unroll
    for (int st = 0; st < 2; ++st)
      #pragma unroll
      for (int r = 0; r < 16; ++r)
        x[st][r] = fmaf(mv[st][r>>2][r&3] + lv[st][r>>2][r&3], SCL, xc[st][r]);

    // ---- online softmax(c): tree max + permlane cross-half max ----
    float mx[8];
    #pragma unroll
    for (int i = 0; i < 8; ++i)
      mx[i] = fmaxf(fmaxf(x[0][i], x[0][i+8]), fmaxf(x[1][i], x[1][i+8]));
    #pragma unroll
    for (int w = 4; w >= 1; w >>= 1)
      #pragma unroll
      for (int i = 0; i < w; ++i) mx[i] = fmaxf(mx[i], mx[i+w]);
    const float tmax = xmax32(mx[0]);

    if (!__all(tmax <= mrun + 8.f)) {          // defer-max THR=8 (log2)
      const float mnew = fmaxf(mrun, tmax);
      const float rs = __builtin_amdgcn_exp2f(mrun - mnew);
      mrun = mnew; lsum *= rs;
      acc[0] *= rs; acc[1] *= rs;              // PV(c-1) already landed
    }
    #pragma unroll
    for (int st = 0; st < 2; ++st)
      #pragma unroll
      for (int i = 0; i < 16; ++i)
        x[st][i] = __builtin_amdgcn_exp2f(x[st][i] - mrun);
    // tree sum (depth ~5 instead of 32-deep serial chain)
    float s8[8];
    #pragma unroll
    for (int i = 0; i < 8; ++i)
      s8[i] = (x[0][i] + x[0][i+8]) + (x[1][i] + x[1][i+8]);
    #pragma unroll
    for (int w = 4; w >= 1; w >>= 1)
      #pragma unroll
      for (int i = 0; i < w; ++i) s8[i] += s8[i+w];
    lsum += s8[0];                              // cross-lane sum deferred

    // ---- pack P(c) -> pf via cvt_pk + permlane32_swap (used next body) ----
    #pragma unroll
    for (int sc = 0; sc < 4; ++sc) {
      const int st = sc >> 1, b = (sc & 1) * 8;
      const unsigned k0 = pku(x[st][b+0], x[st][b+1]);
      const unsigned k1 = pku(x[st][b+2], x[st][b+3]);
      const unsigned s0_ = pku(x[st][b+4], x[st][b+5]);
      const unsigned s1_ = pku(x[st][b+6], x[st][b+7]);
      auto X = __builtin_amdgcn_permlane32_swap(k0, s0_, false, false);
      auto Y = __builtin_amdgcn_permlane32_swap(k1, s1_, false, false);
      union { unsigned u[4]; f16x8 v; } pu;
      pu.u[0] = X[0]; pu.u[1] = Y[0]; pu.u[2] = X[1]; pu.u[3] = Y[1];
      pf[sc] = pu.v;
    }

    // rotate V slots: {p,c,n} -> {c,n,p}
    const int t = sp; sp = scur; scur = sn; sn = t;
  }

  // ---- epilogue: final trailing PV, then normalize + store ----
  pv_step(sp);
  lsum = xsum32(lsum);
  const float inv = 1.f / lsum;
  float* Op = O + (((size_t)n * kL + qrow) * kH + h) * kD;
  #pragma unroll
  for (int dt = 0; dt < 2; ++dt)
    #pragma unroll
    for (int m = 0; m < 4; ++m) {
      f32x4 o;
      o[0] = acc[dt][4*m+0] * inv;
      o[1] = acc[dt][4*m+1] * inv;
      o[2] = acc[dt][4*m+2] * inv;
      o[3] = acc[dt][4*m+3] * inv;
      *reinterpret_cast<f32x4*>(Op + 32*dt + 8*m + 4*hi) = o;
    }
}

extern "C" void kernel_launch(void* const* d_in, const int* in_sizes, int n_in,
                              void* d_out, int out_size, void* d_ws, size_t ws_size,
                              hipStream_t stream) {
  const float* Q   = (const float*)d_in[0];
  const float* K   = (const float*)d_in[1];
  const float* V   = (const float*)d_in[2];
  const float* M   = (const float*)d_in[3];
  const float* KLN = (const float*)d_in[4];
  float* O = (float*)d_out;

  dim3 grid(kN * kH * (kL / 128));  // 512 blocks
  dim3 block(256);                  // 4 waves, 32 queries each
  attn_fwd_kernel<<<grid, block, 0, stream>>>(Q, K, V, M, KLN, O);
}